// Round 5
// baseline (6312.590 us; speedup 1.0000x reference)
//
#include <hip/hip_runtime.h>
#include <hip/hip_fp16.h>
#include <stdint.h>

#define TT 2048
#define BB 16
#define DD 1024
static const size_t H0OFF = 33554432; // 2048*16*1024 floats (start of h section in d_out)

typedef _Float16 f16;
typedef _Float16 f16x2 __attribute__((ext_vector_type(2)));
typedef _Float16 f16x8 __attribute__((ext_vector_type(8)));
typedef float f32x4 __attribute__((ext_vector_type(4)));

// ---------------- threefry + normal (replicates jax.random.normal(key(1),(1024,),f32)) ----
__device__ __forceinline__ float erfinv_xla(float x) {
  float w = -log1pf(-x * x);
  float p;
  if (w < 5.0f) {
    w -= 2.5f;
    p = 2.81022636e-08f;
    p = fmaf(p, w, 3.43273939e-07f);
    p = fmaf(p, w, -3.5233877e-06f);
    p = fmaf(p, w, -4.39150654e-06f);
    p = fmaf(p, w, 0.00021858087f);
    p = fmaf(p, w, -0.00125372503f);
    p = fmaf(p, w, -0.00417768164f);
    p = fmaf(p, w, 0.246640727f);
    p = fmaf(p, w, 1.50140941f);
  } else {
    w = sqrtf(w) - 3.0f;
    p = -0.000200214257f;
    p = fmaf(p, w, 0.000100950558f);
    p = fmaf(p, w, 0.00134934322f);
    p = fmaf(p, w, -0.00367342844f);
    p = fmaf(p, w, 0.00573950773f);
    p = fmaf(p, w, -0.0076224613f);
    p = fmaf(p, w, 0.00943887047f);
    p = fmaf(p, w, 1.00167406f);
    p = fmaf(p, w, 2.83297682f);
  }
  return p * x;
}

__device__ __forceinline__ float bits_to_normal(unsigned bits) {
  unsigned fb = (bits >> 9) | 0x3f800000u;
  float f = __uint_as_float(fb) - 1.0f;          // [0,1)
  const float lo = -0.99999994f;                 // nextafterf(-1,0)
  float u = f * 2.0f + lo;
  u = fmaxf(lo, u);
  return __uint_as_float(0x3fb504f3u) * erfinv_xla(u); // sqrt(2) fp32
}

#define TF_ROUND(r) { x0 += x1; x1 = (x1 << r) | (x1 >> (32 - r)); x1 ^= x0; }

__global__ void k_u0(float* t0, float* u) {
  __shared__ float red[512];
  int i = threadIdx.x; // 512 threads
  unsigned ks0 = 0u, ks1 = 1u, ks2 = 0x1BD11BDAu ^ 0u ^ 1u;
  unsigned x0 = (unsigned)i + ks0;
  unsigned x1 = (unsigned)(i + 512) + ks1;
  TF_ROUND(13) TF_ROUND(15) TF_ROUND(26) TF_ROUND(6)
  x0 += ks1; x1 += ks2 + 1u;
  TF_ROUND(17) TF_ROUND(29) TF_ROUND(16) TF_ROUND(24)
  x0 += ks2; x1 += ks0 + 2u;
  TF_ROUND(13) TF_ROUND(15) TF_ROUND(26) TF_ROUND(6)
  x0 += ks0; x1 += ks1 + 3u;
  TF_ROUND(17) TF_ROUND(29) TF_ROUND(16) TF_ROUND(24)
  x0 += ks1; x1 += ks2 + 4u;
  TF_ROUND(13) TF_ROUND(15) TF_ROUND(26) TF_ROUND(6)
  x0 += ks2; x1 += ks0 + 5u;
  float z0 = bits_to_normal(x0);
  float z1 = bits_to_normal(x1);
  t0[i] = z0; t0[i + 512] = z1;
  red[i] = z0 * z0 + z1 * z1;
  __syncthreads();
  for (int s = 256; s > 0; s >>= 1) { if (i < s) red[i] += red[i + s]; __syncthreads(); }
  float inv = 1.0f / sqrtf(red[0]);
  u[i] = t0[i] * inv; u[i + 512] = t0[i + 512] * inv;
}

// ---------------- power iteration helpers ----------------
__global__ void k_mvT(const float* __restrict__ W, const float* __restrict__ u,
                      float* __restrict__ out) { // out[j] = sum_i W[i,j]*u[i]
  int j = blockIdx.x * 256 + threadIdx.x;
  float acc = 0.f;
  for (int i = 0; i < DD; ++i) acc = fmaf(W[(size_t)i * DD + j], u[i], acc);
  out[j] = acc;
}

__global__ void k_mv(const float* __restrict__ W, const float* __restrict__ v,
                     float* __restrict__ out) { // out[i] = sum_j W[i,j]*v[j]
  int gtid = blockIdx.x * 256 + threadIdx.x;
  int wave = gtid >> 6, lane = threadIdx.x & 63;
  for (int rr = 0; rr < 16; ++rr) {
    int row = wave * 16 + rr;
    float acc = 0.f;
    for (int c = 0; c < 16; ++c) {
      int col = c * 64 + lane;
      acc = fmaf(W[(size_t)row * DD + col], v[col], acc);
    }
    for (int off = 32; off > 0; off >>= 1) acc += __shfl_down(acc, off, 64);
    if (lane == 0) out[row] = acc;
  }
}

__global__ void k_norm(const float* __restrict__ src, float* __restrict__ dst, float eps) {
  __shared__ float red[1024];
  int i = threadIdx.x;
  float xv = src[i];
  red[i] = xv * xv;
  __syncthreads();
  for (int s = 512; s > 0; s >>= 1) { if (i < s) red[i] += red[i + s]; __syncthreads(); }
  float inv = 1.0f / (sqrtf(red[0]) + eps);
  dst[i] = src[i] * inv;
}

__global__ void k_sigma(const float* __restrict__ u, const float* __restrict__ wv,
                        float* __restrict__ scale) {
  __shared__ float red[1024];
  int i = threadIdx.x;
  red[i] = u[i] * wv[i];
  __syncthreads();
  for (int s = 512; s > 0; s >>= 1) { if (i < s) red[i] += red[i + s]; __syncthreads(); }
  if (i == 0) scale[0] = 0.99f / (fabsf(red[0]) + 1e-8f);
}

__global__ void k_castWh(const float* __restrict__ Wh, const float* __restrict__ scale,
                         f16* __restrict__ WhH) {
  int i = blockIdx.x * 256 + threadIdx.x;
  float s = scale[0];
  WhH[i] = (f16)(Wh[i] * s);
}

// ---------------- batched GEMM: C[m,e] = sum_d X[m,d]*W[e,d] + bias[e] (W in f32) ------
__global__ __launch_bounds__(256) void k_gemm(const float* __restrict__ X,
                                              const float* __restrict__ Wt,
                                              const float* __restrict__ bias,
                                              float* __restrict__ Cout) {
  __shared__ __align__(16) f16 Ah[128 * 64];
  __shared__ __align__(16) f16 Bh[128 * 64];
  int m0 = blockIdx.x * 128, n0 = blockIdx.y * 128;
  int tid = threadIdx.x, lane = tid & 63, w = tid >> 6;
  int wm = w & 1, wn = w >> 1;
  int srow = tid >> 3, scol = (tid & 7) * 8;
  f32x4 acc[4][4];
#pragma unroll
  for (int i = 0; i < 4; ++i)
#pragma unroll
    for (int j = 0; j < 4; ++j) acc[i][j] = (f32x4){0.f, 0.f, 0.f, 0.f};

  for (int kt = 0; kt < 16; ++kt) {
    int k0 = kt * 64;
#pragma unroll
    for (int c = 0; c < 4; ++c) {
      int row = c * 32 + srow;
      const float4* sa = (const float4*)(X + (size_t)(m0 + row) * DD + k0 + scol);
      float4 a0 = sa[0], a1 = sa[1];
      f16x8 hv;
      hv[0] = (f16)a0.x; hv[1] = (f16)a0.y; hv[2] = (f16)a0.z; hv[3] = (f16)a0.w;
      hv[4] = (f16)a1.x; hv[5] = (f16)a1.y; hv[6] = (f16)a1.z; hv[7] = (f16)a1.w;
      *(f16x8*)&Ah[row * 64 + scol] = hv;
      const float4* sb = (const float4*)(Wt + (size_t)(n0 + row) * DD + k0 + scol);
      float4 b0 = sb[0], b1 = sb[1];
      f16x8 hw;
      hw[0] = (f16)b0.x; hw[1] = (f16)b0.y; hw[2] = (f16)b0.z; hw[3] = (f16)b0.w;
      hw[4] = (f16)b1.x; hw[5] = (f16)b1.y; hw[6] = (f16)b1.z; hw[7] = (f16)b1.w;
      *(f16x8*)&Bh[row * 64 + scol] = hw;
    }
    __syncthreads();
#pragma unroll
    for (int ks = 0; ks < 2; ++ks) {
      f16x8 af[4], bf[4];
#pragma unroll
      for (int i = 0; i < 4; ++i)
        af[i] = *(const f16x8*)&Ah[(wm * 64 + i * 16 + (lane & 15)) * 64 + ks * 32 + (lane >> 4) * 8];
#pragma unroll
      for (int j = 0; j < 4; ++j)
        bf[j] = *(const f16x8*)&Bh[(wn * 64 + j * 16 + (lane & 15)) * 64 + ks * 32 + (lane >> 4) * 8];
#pragma unroll
      for (int i = 0; i < 4; ++i)
#pragma unroll
        for (int j = 0; j < 4; ++j)
          acc[i][j] = __builtin_amdgcn_mfma_f32_16x16x32_f16(af[i], bf[j], acc[i][j], 0, 0, 0);
    }
    __syncthreads();
  }
#pragma unroll
  for (int j = 0; j < 4; ++j) {
    int col = n0 + wn * 64 + j * 16 + (lane & 15);
    float bs = bias[col];
#pragma unroll
    for (int i = 0; i < 4; ++i) {
      int rbase = m0 + wm * 64 + i * 16 + (lane >> 4) * 4;
#pragma unroll
      for (int r = 0; r < 4; ++r)
        Cout[(size_t)(rbase + r) * DD + col] = acc[i][j][r] + bs;
    }
  }
}

// ---------------- persistent recurrence (LDS-W + dual-path tagged exchange) ----------------
__device__ __forceinline__ float fdot2u(uint32_t a, uint32_t b, float c) {
#if __has_builtin(__builtin_amdgcn_fdot2)
  return __builtin_amdgcn_fdot2(__builtin_bit_cast(f16x2, a),
                                __builtin_bit_cast(f16x2, b), c, false);
#else
  f16x2 av = __builtin_bit_cast(f16x2, a), bv = __builtin_bit_cast(f16x2, b);
  return c + (float)av[0] * (float)bv[0] + (float)av[1] * (float)bv[1];
#endif
}

__device__ __forceinline__ float sigmoid_fast(float v) {
  return 1.0f / (1.0f + __expf(-v));
}
__device__ __forceinline__ float tanh_fast(float v) {
  float t = __expf(-2.0f * fabsf(v));
  float r = (1.0f - t) / (1.0f + t);
  return copysignf(r, v);
}

// fast-path poll load: bypass L1, hit local XCD L2 (sc0)
__device__ __forceinline__ uint32_t load_sc0(const uint32_t* p) {
  uint32_t v;
  asm volatile("global_load_dword %0, %1, off sc0\n\ts_waitcnt vmcnt(0)"
               : "=v"(v) : "v"(p) : "memory");
  return v;
}

// poll one tagged word until its tag == want across all 64 lanes.
// 7 fast (L2) polls : 1 agent (coherence-point) poll -> correct under any placement.
__device__ __forceinline__ uint32_t poll_word(const uint32_t* wp, uint32_t want) {
  uint32_t v;
  int it = 0;
  while (true) {
    if ((it & 7) != 7) {
      v = load_sc0(wp);
    } else {
      v = __hip_atomic_load(wp, __ATOMIC_RELAXED, __HIP_MEMORY_SCOPE_AGENT);
    }
    if (__all((v >> 16) == want)) break;
    ++it;
  }
  return v;
}

// 256-col dot: lane's W row chunk (8x16B, pre-loaded) x h broadcast from LDS
__device__ __forceinline__ float dot256(const uint4 w[8], const uint4* hq4, int b16) {
  float ac[4] = {0.f, 0.f, 0.f, 0.f};
#pragma unroll
  for (int j = 0; j < 8; ++j) {
    uint4 hh = hq4[b16 + j];
    uint4 ww = w[j];
    float a = ac[j & 3];
    a = fdot2u(ww.x, hh.x, a); a = fdot2u(ww.y, hh.y, a);
    a = fdot2u(ww.z, hh.z, a); a = fdot2u(ww.w, hh.w, a);
    ac[j & 3] = a;
  }
  return (ac[0] + ac[1]) + (ac[2] + ac[3]);
}

__global__ __launch_bounds__(256, 1) void k_rec(const float* __restrict__ x,
                                                const float* __restrict__ h0,
                                                const float* __restrict__ b_gate,
                                                const f16* __restrict__ WhH,
                                                uint32_t* __restrict__ hx,
                                                float* __restrict__ d_out) {
  int bid = blockIdx.x;
  // all 16 blocks of a batch land on one XCD under bid%8 round-robin (perf heuristic only)
  int batch = (bid & 7) + ((bid >> 7) << 3);
  int eslice = (bid >> 3) & 15;
  int tid = threadIdx.x, lane = tid & 63, wv = tid >> 6;

  __shared__ __align__(16) f16 Wsh[64 * 1024];   // 128 KB, XOR-swizzled 16B chunks
  __shared__ __align__(16) uint16_t hsh[1024];   // current h as f16
  __shared__ float partial[2][4][64];            // [parity][d-chunk][block-row]

  // ---- stage W slice into LDS (swizzle: 16B-chunk cc of row r at slot cc ^ (r&7)) ----
  {
    int r = tid >> 2, q = tid & 3;
    const uint4* src = (const uint4*)(WhH + (size_t)(64 * eslice + r) * DD + q * 256);
    uint4* dst = (uint4*)Wsh;
#pragma unroll
    for (int j = 0; j < 32; ++j) {
      int cc = q * 32 + j;
      dst[r * 128 + (cc ^ (r & 7))] = src[j];
    }
  }
  // ---- stage h0 (f32 -> f16), 4 elements per thread ----
  {
    const float4* hb = (const float4*)(h0 + (size_t)batch * DD) + tid;
    float4 a = *hb;
    ushort4 pk;
    pk.x = __builtin_bit_cast(uint16_t, (f16)a.x);
    pk.y = __builtin_bit_cast(uint16_t, (f16)a.y);
    pk.z = __builtin_bit_cast(uint16_t, (f16)a.z);
    pk.w = __builtin_bit_cast(uint16_t, (f16)a.w);
    *(ushort4*)&hsh[4 * tid] = pk;
  }

  // tail state (lanes 0..15 of each wave): block-row rr = 16*wv + lane
  float h_own = 0.f, bgv = 0.f, cx_c = 0.f, dr_c = 0.f, xv_c = 0.f;
  int e_g = 64 * eslice + 16 * wv + (lane & 15);
  if (lane < 16) {
    size_t b0 = (size_t)batch * DD + e_g;
    h_own = h0[b0];
    bgv = b_gate[e_g];
    d_out[H0OFF + b0] = h_own;        // h[0]
    cx_c = d_out[b0];                 // cand_x[0]
    dr_c = d_out[H0OFF + 16384 + b0]; // delta_raw[0]
    xv_c = x[b0];
  }
  __syncthreads();

  const uint4* Wsh4 = (const uint4*)Wsh;
  const uint4* hq4 = (const uint4*)hsh;

  // ---- initial partial[0] = W-chunk . h0 ----
  {
    float p = 0.f;
#pragma unroll
    for (int s = 0; s < 4; ++s) {
      uint4 w[8];
#pragma unroll
      for (int j = 0; j < 8; ++j)
        w[j] = Wsh4[lane * 128 + ((32 * wv + 8 * s + j) ^ (lane & 7))];
      p += dot256(w, hq4, 32 * wv + 8 * s);
    }
    partial[0][wv][lane] = p;
  }

#pragma unroll 1
  for (int t = 0; t < TT; ++t) {
    __syncthreads();                               // partial[t&1] complete

    uint32_t want = (uint32_t)(t + 1);
    uint32_t* sl = hx + (size_t)(want & 15u) * (BB * DD) + (size_t)batch * DD;

    // ---- tail: finish 16 rows, publish h(t+1), write outputs, prefetch t+1 streams ----
    if (lane < 16) {
      int rr = 16 * wv + lane;
      const float* pp = &partial[t & 1][0][rr];
      float hdot = (pp[0] + pp[64]) + (pp[128] + pp[192]);
      float dlt = sigmoid_fast(dr_c);
      float cand = tanh_fast(cx_c + hdot);
      float hn = fmaf(dlt, cand - h_own, h_own);
      uint16_t hb = __builtin_bit_cast(uint16_t, (f16)hn);
      uint32_t tagged = (want << 16) | (uint32_t)hb;
      // dual publish: agent store (coherence point, fallback) + plain store (local L2, fast)
      __hip_atomic_store(&sl[e_g], tagged, __ATOMIC_RELAXED, __HIP_MEMORY_SCOPE_AGENT);
      *(volatile uint32_t*)&sl[e_g] = tagged;
      size_t base = (size_t)t * 16384 + (size_t)batch * DD + e_g;
      float z = hn + xv_c + bgv;
      d_out[base] = hn * z * sigmoid_fast(z);   // out[t]  (overwrites consumed cand_x[t])
      d_out[H0OFF + 16384 + base] = hn;         // h[t+1]  (overwrites consumed delta_raw[t])
      h_own = hn;
      if (t + 1 < TT) {
        size_t bn = (size_t)(t + 1) * 16384 + (size_t)batch * DD + e_g;
        cx_c = d_out[bn];
        dr_c = d_out[H0OFF + 16384 + bn];
        xv_c = x[bn];
      }
    }

    // ---- poll + matvec fused, per 64-row subchunk, W prefetched ahead ----
    if (t + 1 < TT) {
      uint4 wA[8], wB[8];
#pragma unroll
      for (int j = 0; j < 8; ++j)
        wA[j] = Wsh4[lane * 128 + ((32 * wv + j) ^ (lane & 7))];
      float psum = 0.f;
#pragma unroll
      for (int s = 0; s < 4; ++s) {
        uint32_t v = poll_word(sl + 256 * wv + 64 * s + lane, want);
        if (s < 3) {
#pragma unroll
          for (int j = 0; j < 8; ++j)
            wB[j] = Wsh4[lane * 128 + ((32 * wv + 8 * (s + 1) + j) ^ (lane & 7))];
        }
        hsh[256 * wv + 64 * s + lane] = (uint16_t)v;   // wave-local stage
        psum += dot256(wA, hq4, 32 * wv + 8 * s);
#pragma unroll
        for (int j = 0; j < 8; ++j) wA[j] = wB[j];
      }
      partial[(t + 1) & 1][wv][lane] = psum;
    }
  }
}

// ---------------- launch ----------------
extern "C" void kernel_launch(void* const* d_in, const int* in_sizes, int n_in,
                              void* d_out_v, int out_size, void* d_ws, size_t ws_size,
                              hipStream_t stream) {
  const float* x  = (const float*)d_in[0];
  const float* h0 = (const float*)d_in[1];
  const float* Wx = (const float*)d_in[2];
  const float* Wh = (const float*)d_in[3];
  const float* Wd = (const float*)d_in[4];
  const float* b  = (const float*)d_in[5];
  const float* bd = (const float*)d_in[6];
  const float* bg = (const float*)d_in[7];
  float* out = (float*)d_out_v;

  char* ws = (char*)d_ws;
  float* u    = (float*)(ws + 0);
  float* v    = (float*)(ws + 4096);
  float* t0   = (float*)(ws + 8192);
  float* sc   = (float*)(ws + 12288);
  uint32_t* hx = (uint32_t*)(ws + 65536);        // 16 slots * 16 batches * 1024 words = 1 MiB
  f16* WhH  = (f16*)(ws + 2097152);              // 2 MiB

  hipMemsetAsync(hx, 0, (size_t)16 * BB * DD * 4, stream);  // clear ring tags (replay safety)

  k_u0<<<1, 512, 0, stream>>>(t0, u);
  for (int it = 0; it < 3; ++it) {
    k_mvT<<<4, 256, 0, stream>>>(Wh, u, t0);
    k_norm<<<1, 1024, 0, stream>>>(t0, v, 1e-8f);
    k_mv<<<16, 256, 0, stream>>>(Wh, v, t0);
    k_norm<<<1, 1024, 0, stream>>>(t0, u, 1e-8f);
  }
  k_sigma<<<1, 1024, 0, stream>>>(u, t0, sc);
  k_castWh<<<4096, 256, 0, stream>>>(Wh, sc, WhH);

  dim3 gg(256, 8, 1);
  k_gemm<<<gg, 256, 0, stream>>>(x, Wx, b, out);                   // cand_x -> out region
  k_gemm<<<gg, 256, 0, stream>>>(x, Wd, bd, out + H0OFF + 16384);  // delta_raw -> h region (+1 slot)

  k_rec<<<256, 256, 0, stream>>>(x, h0, bg, WhH, hx, out);
}

// Round 7
// 5038.296 us; speedup vs baseline: 1.2529x; 1.2529x over previous
//
#include <hip/hip_runtime.h>
#include <hip/hip_fp16.h>
#include <stdint.h>

#define TT 2048
#define BB 16
#define DD 1024
static const size_t H0OFF = 33554432; // 2048*16*1024 floats (start of h section in d_out)

typedef _Float16 f16;
typedef _Float16 f16x2 __attribute__((ext_vector_type(2)));
typedef _Float16 f16x8 __attribute__((ext_vector_type(8)));
typedef float f32x4 __attribute__((ext_vector_type(4)));

// ---------------- threefry + normal (replicates jax.random.normal(key(1),(1024,),f32)) ----
__device__ __forceinline__ float erfinv_xla(float x) {
  float w = -log1pf(-x * x);
  float p;
  if (w < 5.0f) {
    w -= 2.5f;
    p = 2.81022636e-08f;
    p = fmaf(p, w, 3.43273939e-07f);
    p = fmaf(p, w, -3.5233877e-06f);
    p = fmaf(p, w, -4.39150654e-06f);
    p = fmaf(p, w, 0.00021858087f);
    p = fmaf(p, w, -0.00125372503f);
    p = fmaf(p, w, -0.00417768164f);
    p = fmaf(p, w, 0.246640727f);
    p = fmaf(p, w, 1.50140941f);
  } else {
    w = sqrtf(w) - 3.0f;
    p = -0.000200214257f;
    p = fmaf(p, w, 0.000100950558f);
    p = fmaf(p, w, 0.00134934322f);
    p = fmaf(p, w, -0.00367342844f);
    p = fmaf(p, w, 0.00573950773f);
    p = fmaf(p, w, -0.0076224613f);
    p = fmaf(p, w, 0.00943887047f);
    p = fmaf(p, w, 1.00167406f);
    p = fmaf(p, w, 2.83297682f);
  }
  return p * x;
}

__device__ __forceinline__ float bits_to_normal(unsigned bits) {
  unsigned fb = (bits >> 9) | 0x3f800000u;
  float f = __uint_as_float(fb) - 1.0f;          // [0,1)
  const float lo = -0.99999994f;                 // nextafterf(-1,0)
  float u = f * 2.0f + lo;
  u = fmaxf(lo, u);
  return __uint_as_float(0x3fb504f3u) * erfinv_xla(u); // sqrt(2) fp32
}

#define TF_ROUND(r) { x0 += x1; x1 = (x1 << r) | (x1 >> (32 - r)); x1 ^= x0; }

__global__ void k_u0(float* t0, float* u) {
  __shared__ float red[512];
  int i = threadIdx.x; // 512 threads
  unsigned ks0 = 0u, ks1 = 1u, ks2 = 0x1BD11BDAu ^ 0u ^ 1u;
  unsigned x0 = (unsigned)i + ks0;
  unsigned x1 = (unsigned)(i + 512) + ks1;
  TF_ROUND(13) TF_ROUND(15) TF_ROUND(26) TF_ROUND(6)
  x0 += ks1; x1 += ks2 + 1u;
  TF_ROUND(17) TF_ROUND(29) TF_ROUND(16) TF_ROUND(24)
  x0 += ks2; x1 += ks0 + 2u;
  TF_ROUND(13) TF_ROUND(15) TF_ROUND(26) TF_ROUND(6)
  x0 += ks0; x1 += ks1 + 3u;
  TF_ROUND(17) TF_ROUND(29) TF_ROUND(16) TF_ROUND(24)
  x0 += ks1; x1 += ks2 + 4u;
  TF_ROUND(13) TF_ROUND(15) TF_ROUND(26) TF_ROUND(6)
  x0 += ks2; x1 += ks0 + 5u;
  float z0 = bits_to_normal(x0);
  float z1 = bits_to_normal(x1);
  t0[i] = z0; t0[i + 512] = z1;
  red[i] = z0 * z0 + z1 * z1;
  __syncthreads();
  for (int s = 256; s > 0; s >>= 1) { if (i < s) red[i] += red[i + s]; __syncthreads(); }
  float inv = 1.0f / sqrtf(red[0]);
  u[i] = t0[i] * inv; u[i + 512] = t0[i + 512] * inv;
}

// ---------------- power iteration helpers ----------------
__global__ void k_mvT(const float* __restrict__ W, const float* __restrict__ u,
                      float* __restrict__ out) { // out[j] = sum_i W[i,j]*u[i]
  int j = blockIdx.x * 256 + threadIdx.x;
  float acc = 0.f;
  for (int i = 0; i < DD; ++i) acc = fmaf(W[(size_t)i * DD + j], u[i], acc);
  out[j] = acc;
}

__global__ void k_mv(const float* __restrict__ W, const float* __restrict__ v,
                     float* __restrict__ out) { // out[i] = sum_j W[i,j]*v[j]
  int gtid = blockIdx.x * 256 + threadIdx.x;
  int wave = gtid >> 6, lane = threadIdx.x & 63;
  for (int rr = 0; rr < 16; ++rr) {
    int row = wave * 16 + rr;
    float acc = 0.f;
    for (int c = 0; c < 16; ++c) {
      int col = c * 64 + lane;
      acc = fmaf(W[(size_t)row * DD + col], v[col], acc);
    }
    for (int off = 32; off > 0; off >>= 1) acc += __shfl_down(acc, off, 64);
    if (lane == 0) out[row] = acc;
  }
}

__global__ void k_norm(const float* __restrict__ src, float* __restrict__ dst, float eps) {
  __shared__ float red[1024];
  int i = threadIdx.x;
  float xv = src[i];
  red[i] = xv * xv;
  __syncthreads();
  for (int s = 512; s > 0; s >>= 1) { if (i < s) red[i] += red[i + s]; __syncthreads(); }
  float inv = 1.0f / (sqrtf(red[0]) + eps);
  dst[i] = src[i] * inv;
}

__global__ void k_sigma(const float* __restrict__ u, const float* __restrict__ wv,
                        float* __restrict__ scale) {
  __shared__ float red[1024];
  int i = threadIdx.x;
  red[i] = u[i] * wv[i];
  __syncthreads();
  for (int s = 512; s > 0; s >>= 1) { if (i < s) red[i] += red[i + s]; __syncthreads(); }
  if (i == 0) scale[0] = 0.99f / (fabsf(red[0]) + 1e-8f);
}

__global__ void k_castWh(const float* __restrict__ Wh, const float* __restrict__ scale,
                         f16* __restrict__ WhH) {
  int i = blockIdx.x * 256 + threadIdx.x;
  float s = scale[0];
  WhH[i] = (f16)(Wh[i] * s);
}

// ---------------- batched GEMM: C[m,e] = sum_d X[m,d]*W[e,d] + bias[e] (W in f32) ------
__global__ __launch_bounds__(256) void k_gemm(const float* __restrict__ X,
                                              const float* __restrict__ Wt,
                                              const float* __restrict__ bias,
                                              float* __restrict__ Cout) {
  __shared__ __align__(16) f16 Ah[128 * 64];
  __shared__ __align__(16) f16 Bh[128 * 64];
  int m0 = blockIdx.x * 128, n0 = blockIdx.y * 128;
  int tid = threadIdx.x, lane = tid & 63, w = tid >> 6;
  int wm = w & 1, wn = w >> 1;
  int srow = tid >> 3, scol = (tid & 7) * 8;
  f32x4 acc[4][4];
#pragma unroll
  for (int i = 0; i < 4; ++i)
#pragma unroll
    for (int j = 0; j < 4; ++j) acc[i][j] = (f32x4){0.f, 0.f, 0.f, 0.f};

  for (int kt = 0; kt < 16; ++kt) {
    int k0 = kt * 64;
#pragma unroll
    for (int c = 0; c < 4; ++c) {
      int row = c * 32 + srow;
      const float4* sa = (const float4*)(X + (size_t)(m0 + row) * DD + k0 + scol);
      float4 a0 = sa[0], a1 = sa[1];
      f16x8 hv;
      hv[0] = (f16)a0.x; hv[1] = (f16)a0.y; hv[2] = (f16)a0.z; hv[3] = (f16)a0.w;
      hv[4] = (f16)a1.x; hv[5] = (f16)a1.y; hv[6] = (f16)a1.z; hv[7] = (f16)a1.w;
      *(f16x8*)&Ah[row * 64 + scol] = hv;
      const float4* sb = (const float4*)(Wt + (size_t)(n0 + row) * DD + k0 + scol);
      float4 b0 = sb[0], b1 = sb[1];
      f16x8 hw;
      hw[0] = (f16)b0.x; hw[1] = (f16)b0.y; hw[2] = (f16)b0.z; hw[3] = (f16)b0.w;
      hw[4] = (f16)b1.x; hw[5] = (f16)b1.y; hw[6] = (f16)b1.z; hw[7] = (f16)b1.w;
      *(f16x8*)&Bh[row * 64 + scol] = hw;
    }
    __syncthreads();
#pragma unroll
    for (int ks = 0; ks < 2; ++ks) {
      f16x8 af[4], bf[4];
#pragma unroll
      for (int i = 0; i < 4; ++i)
        af[i] = *(const f16x8*)&Ah[(wm * 64 + i * 16 + (lane & 15)) * 64 + ks * 32 + (lane >> 4) * 8];
#pragma unroll
      for (int j = 0; j < 4; ++j)
        bf[j] = *(const f16x8*)&Bh[(wn * 64 + j * 16 + (lane & 15)) * 64 + ks * 32 + (lane >> 4) * 8];
#pragma unroll
      for (int i = 0; i < 4; ++i)
#pragma unroll
        for (int j = 0; j < 4; ++j)
          acc[i][j] = __builtin_amdgcn_mfma_f32_16x16x32_f16(af[i], bf[j], acc[i][j], 0, 0, 0);
    }
    __syncthreads();
  }
#pragma unroll
  for (int j = 0; j < 4; ++j) {
    int col = n0 + wn * 64 + j * 16 + (lane & 15);
    float bs = bias[col];
#pragma unroll
    for (int i = 0; i < 4; ++i) {
      int rbase = m0 + wm * 64 + i * 16 + (lane >> 4) * 4;
#pragma unroll
      for (int r = 0; r < 4; ++r)
        Cout[(size_t)(rbase + r) * DD + col] = acc[i][j][r] + bs;
    }
  }
}

// ---------------- persistent recurrence (tagged exchange + transposed LDS W) ------------
__device__ __forceinline__ float fdot2u(uint32_t a, uint32_t b, float c) {
#if __has_builtin(__builtin_amdgcn_fdot2)
  return __builtin_amdgcn_fdot2(__builtin_bit_cast(f16x2, a),
                                __builtin_bit_cast(f16x2, b), c, false);
#else
  f16x2 av = __builtin_bit_cast(f16x2, a), bv = __builtin_bit_cast(f16x2, b);
  return c + (float)av[0] * (float)bv[0] + (float)av[1] * (float)bv[1];
#endif
}

__device__ __forceinline__ float sigmoid_fast(float v) {
  return 1.0f / (1.0f + __expf(-v));
}
__device__ __forceinline__ float tanh_fast(float v) {
  float t = __expf(-2.0f * fabsf(v));
  float r = (1.0f - t) / (1.0f + t);
  return copysignf(r, v);
}

__global__ __launch_bounds__(256, 1) void k_rec(const float* __restrict__ x,
                                                const float* __restrict__ h0,
                                                const float* __restrict__ b_gate,
                                                const f16* __restrict__ WhH,
                                                uint32_t* __restrict__ hx,
                                                float* __restrict__ d_out) {
  int bid = blockIdx.x;
  int batch = bid & 15;          // batch-mates share bid%8 -> one XCD under round-robin (perf only)
  int eslice = bid >> 4;         // 0..15 : this block produces rows [64*eslice, 64*eslice+64)
  int tid = threadIdx.x, lane = tid & 63, wv = tid >> 6;

  // W slice TRANSPOSED in LDS: WT[d4 * 64 + row], d4 = f16x2 column index (0..511).
  // Matvec read WT[d4*64 + lane] -> bank = lane%32, 2 lanes/bank = conflict-FREE (m136).
  __shared__ uint32_t WT[512 * 64];                 // 128 KB
  __shared__ __align__(16) uint16_t hsh[1024];      // h_t as f16
  __shared__ float partial[4][64];                  // [d-chunk][block-row]

  // ---- stage W transposed (once): thread = (row r = tid>>2, quarter q = tid&3) ----
  {
    int r = tid >> 2, q = tid & 3;
    const uint32_t* src = (const uint32_t*)(WhH + (size_t)(64 * eslice + r) * DD) + q * 128;
#pragma unroll 8
    for (int j = 0; j < 128; ++j)
      WT[(q * 128 + j) * 64 + r] = src[j];
  }
  // ---- stage h0 (f32 -> f16), 4 elements per thread ----
  {
    const float* hb = h0 + (size_t)batch * DD + 4 * tid;
    float a0 = hb[0], a1 = hb[1], a2 = hb[2], a3 = hb[3];
    uint32_t lo = ((uint32_t)__builtin_bit_cast(uint16_t, (f16)a0)) |
                  ((uint32_t)__builtin_bit_cast(uint16_t, (f16)a1) << 16);
    uint32_t hi = ((uint32_t)__builtin_bit_cast(uint16_t, (f16)a2)) |
                  ((uint32_t)__builtin_bit_cast(uint16_t, (f16)a3) << 16);
    uint2 pk; pk.x = lo; pk.y = hi;
    ((uint2*)hsh)[tid] = pk;                        // uint16 idx 4*tid .. 4*tid+3
  }

  // tail state (wave 0, one row per lane): global row e = 64*eslice + lane
  float h_own = 0.f, bgv = 0.f, cx_c = 0.f, dr_c = 0.f, xv_c = 0.f;
  int e_g = 64 * eslice + lane;
  if (wv == 0) {
    size_t b0 = (size_t)batch * DD + e_g;
    h_own = h0[b0];
    bgv = b_gate[e_g];
    d_out[H0OFF + b0] = h_own;        // h[0]
    cx_c = d_out[b0];                 // cand_x[0]
    dr_c = d_out[H0OFF + 16384 + b0]; // delta_raw[0]
    xv_c = x[b0];
  }
  __syncthreads();

  const uint4* hq4 = (const uint4*)hsh;

#pragma unroll 1
  for (int t = 0; t < TT; ++t) {
    // off-critical-path: wave0 prefetches next step's streams
    float cx_n = 0.f, dr_n = 0.f, xv_n = 0.f;
    if (wv == 0 && t + 1 < TT) {
      size_t bn = (size_t)(t + 1) * 16384 + (size_t)batch * DD + e_g;
      cx_n = d_out[bn];
      dr_n = d_out[H0OFF + 16384 + bn];
      xv_n = x[bn];
    }

    // matvec over this wave's 256-d chunk; W from LDS (conflict-free), h broadcast
    float a0 = 0.f, a1 = 0.f, a2 = 0.f, a3 = 0.f;
#pragma unroll
    for (int k = 0; k < 32; ++k) {
      uint4 hh = hq4[32 * wv + k];                 // broadcast (same addr all lanes)
      int d4 = 128 * wv + 4 * k;
      a0 = fdot2u(WT[(d4 + 0) * 64 + lane], hh.x, a0);
      a1 = fdot2u(WT[(d4 + 1) * 64 + lane], hh.y, a1);
      a2 = fdot2u(WT[(d4 + 2) * 64 + lane], hh.z, a2);
      a3 = fdot2u(WT[(d4 + 3) * 64 + lane], hh.w, a3);
    }
    partial[wv][lane] = (a0 + a1) + (a2 + a3);
    __syncthreads();                                // barrier A

    uint32_t want = (uint32_t)(t + 1);
    uint32_t* slot = hx + (size_t)(want & 15u) * (BB * DD) + (size_t)batch * DD;

    // tail: wave0, one row per lane
    if (wv == 0) {
      float hdot = (partial[0][lane] + partial[1][lane]) +
                   (partial[2][lane] + partial[3][lane]);
      float dlt = sigmoid_fast(dr_c);
      float cand = tanh_fast(cx_c + hdot);
      float hn = fmaf(dlt, cand - h_own, h_own);
      // critical path first: publish tagged h
      uint16_t hb = __builtin_bit_cast(uint16_t, (f16)hn);
      __hip_atomic_store(&slot[e_g], (want << 16) | (uint32_t)hb,
                         __ATOMIC_RELAXED, __HIP_MEMORY_SCOPE_AGENT);
      size_t base = (size_t)t * 16384 + (size_t)batch * DD + e_g;
      float z = hn + xv_c + bgv;
      d_out[base] = hn * z * sigmoid_fast(z);   // out[t]  (overwrites consumed cand_x[t])
      d_out[H0OFF + 16384 + base] = hn;         // h[t+1]  (overwrites consumed delta_raw[t])
      h_own = hn; cx_c = cx_n; dr_c = dr_n; xv_c = xv_n;
    }

    if (t + 1 < TT) {
      // single-stage data poll: thread owns 4 contiguous tagged words (the poll IS the load)
      uint32_t* wp = slot + 4 * tid;
      uint32_t w0, w1, w2, w3;
      while (true) {
        w0 = __hip_atomic_load(wp + 0, __ATOMIC_RELAXED, __HIP_MEMORY_SCOPE_AGENT);
        w1 = __hip_atomic_load(wp + 1, __ATOMIC_RELAXED, __HIP_MEMORY_SCOPE_AGENT);
        w2 = __hip_atomic_load(wp + 2, __ATOMIC_RELAXED, __HIP_MEMORY_SCOPE_AGENT);
        w3 = __hip_atomic_load(wp + 3, __ATOMIC_RELAXED, __HIP_MEMORY_SCOPE_AGENT);
        bool ok = ((w0 >> 16) == want) & ((w1 >> 16) == want) &
                  ((w2 >> 16) == want) & ((w3 >> 16) == want);
        if (__all(ok)) break;
      }
      // pack 4 f16 and store at uint16 indices 4*tid..4*tid+3 (FIX: uint2 store, not uint16)
      uint2 pk;
      pk.x = (w0 & 0xffffu) | (w1 << 16);
      pk.y = (w2 & 0xffffu) | (w3 << 16);
      ((uint2*)hsh)[tid] = pk;
      __syncthreads();                              // barrier B
    }
  }
}

// ---------------- launch ----------------
extern "C" void kernel_launch(void* const* d_in, const int* in_sizes, int n_in,
                              void* d_out_v, int out_size, void* d_ws, size_t ws_size,
                              hipStream_t stream) {
  const float* x  = (const float*)d_in[0];
  const float* h0 = (const float*)d_in[1];
  const float* Wx = (const float*)d_in[2];
  const float* Wh = (const float*)d_in[3];
  const float* Wd = (const float*)d_in[4];
  const float* b  = (const float*)d_in[5];
  const float* bd = (const float*)d_in[6];
  const float* bg = (const float*)d_in[7];
  float* out = (float*)d_out_v;

  char* ws = (char*)d_ws;
  float* u    = (float*)(ws + 0);
  float* v    = (float*)(ws + 4096);
  float* t0   = (float*)(ws + 8192);
  float* sc   = (float*)(ws + 12288);
  uint32_t* hx = (uint32_t*)(ws + 65536);        // 16 slots * 16 batches * 1024 words = 1 MiB
  f16* WhH  = (f16*)(ws + 2097152);              // 2 MiB

  hipMemsetAsync(hx, 0, (size_t)16 * BB * DD * 4, stream);  // clear ring tags (replay safety)

  k_u0<<<1, 512, 0, stream>>>(t0, u);
  for (int it = 0; it < 3; ++it) {
    k_mvT<<<4, 256, 0, stream>>>(Wh, u, t0);
    k_norm<<<1, 1024, 0, stream>>>(t0, v, 1e-8f);
    k_mv<<<16, 256, 0, stream>>>(Wh, v, t0);
    k_norm<<<1, 1024, 0, stream>>>(t0, u, 1e-8f);
  }
  k_sigma<<<1, 1024, 0, stream>>>(u, t0, sc);
  k_castWh<<<4096, 256, 0, stream>>>(Wh, sc, WhH);

  dim3 gg(256, 8, 1);
  k_gemm<<<gg, 256, 0, stream>>>(x, Wx, b, out);                   // cand_x -> out region
  k_gemm<<<gg, 256, 0, stream>>>(x, Wd, bd, out + H0OFF + 16384);  // delta_raw -> h region (+1 slot)

  k_rec<<<256, 256, 0, stream>>>(x, h0, bg, WhH, hx, out);
}

// Round 9
// 4848.357 us; speedup vs baseline: 1.3020x; 1.0392x over previous
//
#include <hip/hip_runtime.h>
#include <hip/hip_fp16.h>
#include <stdint.h>

#define TT 2048
#define BB 16
#define DD 1024
static const size_t H0OFF = 33554432; // 2048*16*1024 floats (start of h section in d_out)

typedef _Float16 f16;
typedef _Float16 f16x2 __attribute__((ext_vector_type(2)));
typedef _Float16 f16x8 __attribute__((ext_vector_type(8)));
typedef float f32x4 __attribute__((ext_vector_type(4)));
typedef unsigned u32x2 __attribute__((ext_vector_type(2)));
typedef unsigned u32x4 __attribute__((ext_vector_type(4)));

// ---------------- threefry + normal (replicates jax.random.normal(key(1),(1024,),f32)) ----
__device__ __forceinline__ float erfinv_xla(float x) {
  float w = -log1pf(-x * x);
  float p;
  if (w < 5.0f) {
    w -= 2.5f;
    p = 2.81022636e-08f;
    p = fmaf(p, w, 3.43273939e-07f);
    p = fmaf(p, w, -3.5233877e-06f);
    p = fmaf(p, w, -4.39150654e-06f);
    p = fmaf(p, w, 0.00021858087f);
    p = fmaf(p, w, -0.00125372503f);
    p = fmaf(p, w, -0.00417768164f);
    p = fmaf(p, w, 0.246640727f);
    p = fmaf(p, w, 1.50140941f);
  } else {
    w = sqrtf(w) - 3.0f;
    p = -0.000200214257f;
    p = fmaf(p, w, 0.000100950558f);
    p = fmaf(p, w, 0.00134934322f);
    p = fmaf(p, w, -0.00367342844f);
    p = fmaf(p, w, 0.00573950773f);
    p = fmaf(p, w, -0.0076224613f);
    p = fmaf(p, w, 0.00943887047f);
    p = fmaf(p, w, 1.00167406f);
    p = fmaf(p, w, 2.83297682f);
  }
  return p * x;
}

__device__ __forceinline__ float bits_to_normal(unsigned bits) {
  unsigned fb = (bits >> 9) | 0x3f800000u;
  float f = __uint_as_float(fb) - 1.0f;          // [0,1)
  const float lo = -0.99999994f;                 // nextafterf(-1,0)
  float u = f * 2.0f + lo;
  u = fmaxf(lo, u);
  return __uint_as_float(0x3fb504f3u) * erfinv_xla(u); // sqrt(2) fp32
}

#define TF_ROUND(r) { x0 += x1; x1 = (x1 << r) | (x1 >> (32 - r)); x1 ^= x0; }

__global__ void k_u0(float* t0, float* u) {
  __shared__ float red[512];
  int i = threadIdx.x; // 512 threads
  unsigned ks0 = 0u, ks1 = 1u, ks2 = 0x1BD11BDAu ^ 0u ^ 1u;
  unsigned x0 = (unsigned)i + ks0;
  unsigned x1 = (unsigned)(i + 512) + ks1;
  TF_ROUND(13) TF_ROUND(15) TF_ROUND(26) TF_ROUND(6)
  x0 += ks1; x1 += ks2 + 1u;
  TF_ROUND(17) TF_ROUND(29) TF_ROUND(16) TF_ROUND(24)
  x0 += ks2; x1 += ks0 + 2u;
  TF_ROUND(13) TF_ROUND(15) TF_ROUND(26) TF_ROUND(6)
  x0 += ks0; x1 += ks1 + 3u;
  TF_ROUND(17) TF_ROUND(29) TF_ROUND(16) TF_ROUND(24)
  x0 += ks1; x1 += ks2 + 4u;
  TF_ROUND(13) TF_ROUND(15) TF_ROUND(26) TF_ROUND(6)
  x0 += ks2; x1 += ks0 + 5u;
  float z0 = bits_to_normal(x0);
  float z1 = bits_to_normal(x1);
  t0[i] = z0; t0[i + 512] = z1;
  red[i] = z0 * z0 + z1 * z1;
  __syncthreads();
  for (int s = 256; s > 0; s >>= 1) { if (i < s) red[i] += red[i + s]; __syncthreads(); }
  float inv = 1.0f / sqrtf(red[0]);
  u[i] = t0[i] * inv; u[i + 512] = t0[i + 512] * inv;
}

// ---------------- power iteration helpers ----------------
__global__ void k_mvT(const float* __restrict__ W, const float* __restrict__ u,
                      float* __restrict__ out) { // out[j] = sum_i W[i,j]*u[i]
  int j = blockIdx.x * 256 + threadIdx.x;
  float acc = 0.f;
  for (int i = 0; i < DD; ++i) acc = fmaf(W[(size_t)i * DD + j], u[i], acc);
  out[j] = acc;
}

__global__ void k_mv(const float* __restrict__ W, const float* __restrict__ v,
                     float* __restrict__ out) { // out[i] = sum_j W[i,j]*v[j]
  int gtid = blockIdx.x * 256 + threadIdx.x;
  int wave = gtid >> 6, lane = threadIdx.x & 63;
  for (int rr = 0; rr < 16; ++rr) {
    int row = wave * 16 + rr;
    float acc = 0.f;
    for (int c = 0; c < 16; ++c) {
      int col = c * 64 + lane;
      acc = fmaf(W[(size_t)row * DD + col], v[col], acc);
    }
    for (int off = 32; off > 0; off >>= 1) acc += __shfl_down(acc, off, 64);
    if (lane == 0) out[row] = acc;
  }
}

__global__ void k_norm(const float* __restrict__ src, float* __restrict__ dst, float eps) {
  __shared__ float red[1024];
  int i = threadIdx.x;
  float xv = src[i];
  red[i] = xv * xv;
  __syncthreads();
  for (int s = 512; s > 0; s >>= 1) { if (i < s) red[i] += red[i + s]; __syncthreads(); }
  float inv = 1.0f / (sqrtf(red[0]) + eps);
  dst[i] = src[i] * inv;
}

__global__ void k_sigma(const float* __restrict__ u, const float* __restrict__ wv,
                        float* __restrict__ scale) {
  __shared__ float red[1024];
  int i = threadIdx.x;
  red[i] = u[i] * wv[i];
  __syncthreads();
  for (int s = 512; s > 0; s >>= 1) { if (i < s) red[i] += red[i + s]; __syncthreads(); }
  if (i == 0) scale[0] = 0.99f / (fabsf(red[0]) + 1e-8f);
}

__global__ void k_castWh(const float* __restrict__ Wh, const float* __restrict__ scale,
                         f16* __restrict__ WhH) {
  int i = blockIdx.x * 256 + threadIdx.x;
  float s = scale[0];
  WhH[i] = (f16)(Wh[i] * s);
}

// ---------------- batched GEMM: C[m,e] = sum_d X[m,d]*W[e,d] + bias[e] (W in f32) ------
__global__ __launch_bounds__(256) void k_gemm(const float* __restrict__ X,
                                              const float* __restrict__ Wt,
                                              const float* __restrict__ bias,
                                              float* __restrict__ Cout) {
  __shared__ __align__(16) f16 Ah[128 * 64];
  __shared__ __align__(16) f16 Bh[128 * 64];
  int m0 = blockIdx.x * 128, n0 = blockIdx.y * 128;
  int tid = threadIdx.x, lane = tid & 63, w = tid >> 6;
  int wm = w & 1, wn = w >> 1;
  int srow = tid >> 3, scol = (tid & 7) * 8;
  f32x4 acc[4][4];
#pragma unroll
  for (int i = 0; i < 4; ++i)
#pragma unroll
    for (int j = 0; j < 4; ++j) acc[i][j] = (f32x4){0.f, 0.f, 0.f, 0.f};

  for (int kt = 0; kt < 16; ++kt) {
    int k0 = kt * 64;
#pragma unroll
    for (int c = 0; c < 4; ++c) {
      int row = c * 32 + srow;
      const float4* sa = (const float4*)(X + (size_t)(m0 + row) * DD + k0 + scol);
      float4 a0 = sa[0], a1 = sa[1];
      f16x8 hv;
      hv[0] = (f16)a0.x; hv[1] = (f16)a0.y; hv[2] = (f16)a0.z; hv[3] = (f16)a0.w;
      hv[4] = (f16)a1.x; hv[5] = (f16)a1.y; hv[6] = (f16)a1.z; hv[7] = (f16)a1.w;
      *(f16x8*)&Ah[row * 64 + scol] = hv;
      const float4* sb = (const float4*)(Wt + (size_t)(n0 + row) * DD + k0 + scol);
      float4 b0 = sb[0], b1 = sb[1];
      f16x8 hw;
      hw[0] = (f16)b0.x; hw[1] = (f16)b0.y; hw[2] = (f16)b0.z; hw[3] = (f16)b0.w;
      hw[4] = (f16)b1.x; hw[5] = (f16)b1.y; hw[6] = (f16)b1.z; hw[7] = (f16)b1.w;
      *(f16x8*)&Bh[row * 64 + scol] = hw;
    }
    __syncthreads();
#pragma unroll
    for (int ks = 0; ks < 2; ++ks) {
      f16x8 af[4], bf[4];
#pragma unroll
      for (int i = 0; i < 4; ++i)
        af[i] = *(const f16x8*)&Ah[(wm * 64 + i * 16 + (lane & 15)) * 64 + ks * 32 + (lane >> 4) * 8];
#pragma unroll
      for (int j = 0; j < 4; ++j)
        bf[j] = *(const f16x8*)&Bh[(wn * 64 + j * 16 + (lane & 15)) * 64 + ks * 32 + (lane >> 4) * 8];
#pragma unroll
      for (int i = 0; i < 4; ++i)
#pragma unroll
        for (int j = 0; j < 4; ++j)
          acc[i][j] = __builtin_amdgcn_mfma_f32_16x16x32_f16(af[i], bf[j], acc[i][j], 0, 0, 0);
    }
    __syncthreads();
  }
#pragma unroll
  for (int j = 0; j < 4; ++j) {
    int col = n0 + wn * 64 + j * 16 + (lane & 15);
    float bs = bias[col];
#pragma unroll
    for (int i = 0; i < 4; ++i) {
      int rbase = m0 + wm * 64 + i * 16 + (lane >> 4) * 4;
#pragma unroll
      for (int r = 0; r < 4; ++r)
        Cout[(size_t)(rbase + r) * DD + col] = acc[i][j][r] + bs;
    }
  }
}

// ---------------- persistent recurrence: W in VGPRs + dual-path tagged exchange ---------
__device__ __forceinline__ float fdot2u(uint32_t a, uint32_t b, float c) {
#if __has_builtin(__builtin_amdgcn_fdot2)
  return __builtin_amdgcn_fdot2(__builtin_bit_cast(f16x2, a),
                                __builtin_bit_cast(f16x2, b), c, false);
#else
  f16x2 av = __builtin_bit_cast(f16x2, a), bv = __builtin_bit_cast(f16x2, b);
  return c + (float)av[0] * (float)bv[0] + (float)av[1] * (float)bv[1];
#endif
}

__device__ __forceinline__ float sigmoid_fast(float v) {
  return 1.0f / (1.0f + __expf(-v));
}
__device__ __forceinline__ float tanh_fast(float v) {
  float t = __expf(-2.0f * fabsf(v));
  float r = (1.0f - t) / (1.0f + t);
  return copysignf(r, v);
}

// fast-path poll: bypass L1, hit local-XCD L2 (sc0). 8 bytes.
__device__ __forceinline__ u32x2 load2_sc0(const uint32_t* p) {
  u32x2 v;
  asm volatile("global_load_dwordx2 %0, %1, off sc0\n\ts_waitcnt vmcnt(0)"
               : "=v"(v) : "v"(p) : "memory");
  return v;
}

__global__ __launch_bounds__(512, 1) void k_rec(const float* __restrict__ x,
                                                const float* __restrict__ h0,
                                                const float* __restrict__ b_gate,
                                                const f16* __restrict__ WhH,
                                                uint32_t* __restrict__ hxF,
                                                uint32_t* __restrict__ hxS,
                                                float* __restrict__ d_out) {
  int bid = blockIdx.x;
  int batch = bid & 15;      // batch-mates share bid%8 -> one XCD under round-robin (fast path)
  int eslice = bid >> 4;     // 0..15 : block produces rows [64*eslice, 64*eslice+64)
  int tid = threadIdx.x, lane = tid & 63, wv = tid >> 6;   // wv in [0,8)

  __shared__ __align__(16) uint16_t hsh[1024];   // h_t as f16; wave w owns f16 [128w,128w+128)
  __shared__ float partial[2][8][64];            // [parity][d-chunk][block-row]

  // ---- W into registers: row = 64*eslice+lane, cols [128*wv, 128*wv+128) = 16 u32x4 ----
  const u32x4* wp = (const u32x4*)(WhH + (size_t)(64 * eslice + lane) * DD + 128 * wv);
  u32x4 w0 = wp[0],  w1 = wp[1],  w2 = wp[2],  w3 = wp[3];
  u32x4 w4 = wp[4],  w5 = wp[5],  w6 = wp[6],  w7 = wp[7];
  u32x4 w8 = wp[8],  w9 = wp[9],  w10 = wp[10], w11 = wp[11];
  u32x4 w12 = wp[12], w13 = wp[13], w14 = wp[14], w15 = wp[15];
  asm volatile("" : "+v"(w0), "+v"(w1), "+v"(w2), "+v"(w3));
  asm volatile("" : "+v"(w4), "+v"(w5), "+v"(w6), "+v"(w7));
  asm volatile("" : "+v"(w8), "+v"(w9), "+v"(w10), "+v"(w11));
  asm volatile("" : "+v"(w12), "+v"(w13), "+v"(w14), "+v"(w15));

  // ---- stage h0: thread covers f16 idx [2*tid, 2*tid+2) ----
  {
    float2 hv = *(const float2*)(h0 + (size_t)batch * DD + 2 * tid);
    uint32_t pk = ((uint32_t)__builtin_bit_cast(uint16_t, (f16)hv.x)) |
                  ((uint32_t)__builtin_bit_cast(uint16_t, (f16)hv.y) << 16);
    ((uint32_t*)hsh)[tid] = pk;
  }

  // ---- wave0 tail state: one row per lane ----
  float h_own = 0.f, bgv = 0.f, cx_c = 0.f, dr_c = 0.f, xv_c = 0.f;
  int e_g = 64 * eslice + lane;
  if (wv == 0) {
    __builtin_amdgcn_s_setprio(1);     // tail wave is the critical path
    size_t b0 = (size_t)batch * DD + e_g;
    h_own = h0[b0];
    bgv = b_gate[e_g];
    d_out[H0OFF + b0] = h_own;         // h[0]
    cx_c = d_out[b0];                  // cand_x[0]
    dr_c = d_out[H0OFF + 16384 + b0];  // delta_raw[0]
    xv_c = x[b0];
  }
  __syncthreads();

  const u32x4* hq4 = (const u32x4*)hsh;

#pragma unroll 1
  for (int t = 0; t < TT; ++t) {
    // ---- poll h(t) (t>=1): thread owns 2 contiguous tagged words; wave-private stage ----
    if (t > 0) {
      uint32_t want = (uint32_t)t;
      size_t soff = (size_t)(want & 15u) * (BB * DD) + (size_t)batch * DD + 2 * tid;
      const uint32_t* fp = hxF + soff;
      const uint32_t* sp = hxS + soff;
      uint32_t a0w, a1w;
      int it = 0;
      while (true) {
        if ((it & 3) == 3) {       // agent fallback (correct under any placement)
          uint64_t q = __hip_atomic_load((const uint64_t*)sp, __ATOMIC_RELAXED,
                                         __HIP_MEMORY_SCOPE_AGENT);
          a0w = (uint32_t)q; a1w = (uint32_t)(q >> 32);
        } else {                   // fast local-XCD L2 path
          u32x2 q = load2_sc0(fp);
          a0w = q[0]; a1w = q[1];
        }
        bool ok = ((a0w >> 16) == want) & ((a1w >> 16) == want);
        if (__all(ok)) break;
        ++it;
      }
      ((uint32_t*)hsh)[tid] = (a0w & 0xffffu) | (a1w << 16);
      asm volatile("s_waitcnt lgkmcnt(0)" ::: "memory");  // wave-local ds_write->ds_read
    }

    // ---- wave0: prefetch next step's streams (hidden under matvec+barrier) ----
    float cx_n = 0.f, dr_n = 0.f, xv_n = 0.f;
    if (wv == 0 && t + 1 < TT) {
      size_t bn = (size_t)(t + 1) * 16384 + (size_t)batch * DD + e_g;
      cx_n = d_out[bn];
      dr_n = d_out[H0OFF + 16384 + bn];
      xv_n = x[bn];
    }

    // ---- matvec: 64 fdot2 per thread, W in registers, h broadcast from LDS ----
    {
      float a0 = 0.f, a1 = 0.f, a2 = 0.f, a3 = 0.f;
      u32x4 hh;
      hh = hq4[16 * wv + 0];  a0 = fdot2u(w0[0], hh[0], a0);  a0 = fdot2u(w0[1], hh[1], a0);  a0 = fdot2u(w0[2], hh[2], a0);  a0 = fdot2u(w0[3], hh[3], a0);
      hh = hq4[16 * wv + 1];  a1 = fdot2u(w1[0], hh[0], a1);  a1 = fdot2u(w1[1], hh[1], a1);  a1 = fdot2u(w1[2], hh[2], a1);  a1 = fdot2u(w1[3], hh[3], a1);
      hh = hq4[16 * wv + 2];  a2 = fdot2u(w2[0], hh[0], a2);  a2 = fdot2u(w2[1], hh[1], a2);  a2 = fdot2u(w2[2], hh[2], a2);  a2 = fdot2u(w2[3], hh[3], a2);
      hh = hq4[16 * wv + 3];  a3 = fdot2u(w3[0], hh[0], a3);  a3 = fdot2u(w3[1], hh[1], a3);  a3 = fdot2u(w3[2], hh[2], a3);  a3 = fdot2u(w3[3], hh[3], a3);
      hh = hq4[16 * wv + 4];  a0 = fdot2u(w4[0], hh[0], a0);  a0 = fdot2u(w4[1], hh[1], a0);  a0 = fdot2u(w4[2], hh[2], a0);  a0 = fdot2u(w4[3], hh[3], a0);
      hh = hq4[16 * wv + 5];  a1 = fdot2u(w5[0], hh[0], a1);  a1 = fdot2u(w5[1], hh[1], a1);  a1 = fdot2u(w5[2], hh[2], a1);  a1 = fdot2u(w5[3], hh[3], a1);
      hh = hq4[16 * wv + 6];  a2 = fdot2u(w6[0], hh[0], a2);  a2 = fdot2u(w6[1], hh[1], a2);  a2 = fdot2u(w6[2], hh[2], a2);  a2 = fdot2u(w6[3], hh[3], a2);
      hh = hq4[16 * wv + 7];  a3 = fdot2u(w7[0], hh[0], a3);  a3 = fdot2u(w7[1], hh[1], a3);  a3 = fdot2u(w7[2], hh[2], a3);  a3 = fdot2u(w7[3], hh[3], a3);
      hh = hq4[16 * wv + 8];  a0 = fdot2u(w8[0], hh[0], a0);  a0 = fdot2u(w8[1], hh[1], a0);  a0 = fdot2u(w8[2], hh[2], a0);  a0 = fdot2u(w8[3], hh[3], a0);
      hh = hq4[16 * wv + 9];  a1 = fdot2u(w9[0], hh[0], a1);  a1 = fdot2u(w9[1], hh[1], a1);  a1 = fdot2u(w9[2], hh[2], a1);  a1 = fdot2u(w9[3], hh[3], a1);
      hh = hq4[16 * wv + 10]; a2 = fdot2u(w10[0], hh[0], a2); a2 = fdot2u(w10[1], hh[1], a2); a2 = fdot2u(w10[2], hh[2], a2); a2 = fdot2u(w10[3], hh[3], a2);
      hh = hq4[16 * wv + 11]; a3 = fdot2u(w11[0], hh[0], a3); a3 = fdot2u(w11[1], hh[1], a3); a3 = fdot2u(w11[2], hh[2], a3); a3 = fdot2u(w11[3], hh[3], a3);
      hh = hq4[16 * wv + 12]; a0 = fdot2u(w12[0], hh[0], a0); a0 = fdot2u(w12[1], hh[1], a0); a0 = fdot2u(w12[2], hh[2], a0); a0 = fdot2u(w12[3], hh[3], a0);
      hh = hq4[16 * wv + 13]; a1 = fdot2u(w13[0], hh[0], a1); a1 = fdot2u(w13[1], hh[1], a1); a1 = fdot2u(w13[2], hh[2], a1); a1 = fdot2u(w13[3], hh[3], a1);
      hh = hq4[16 * wv + 14]; a2 = fdot2u(w14[0], hh[0], a2); a2 = fdot2u(w14[1], hh[1], a2); a2 = fdot2u(w14[2], hh[2], a2); a2 = fdot2u(w14[3], hh[3], a2);
      hh = hq4[16 * wv + 15]; a3 = fdot2u(w15[0], hh[0], a3); a3 = fdot2u(w15[1], hh[1], a3); a3 = fdot2u(w15[2], hh[2], a3); a3 = fdot2u(w15[3], hh[3], a3);
      partial[t & 1][wv][lane] = (a0 + a1) + (a2 + a3);
    }
    __syncthreads();                              // the ONE barrier per step

    // ---- tail: wave0 finishes 64 rows, publishes h(t+1) on both paths ----
    if (wv == 0) {
      const float* pp = &partial[t & 1][0][lane];
      float hdot = ((pp[0] + pp[64]) + (pp[128] + pp[192])) +
                   ((pp[256] + pp[320]) + (pp[384] + pp[448]));
      float dlt = sigmoid_fast(dr_c);
      float cand = tanh_fast(cx_c + hdot);
      float hn = fmaf(dlt, cand - h_own, h_own);
      uint32_t want1 = (uint32_t)(t + 1);
      uint16_t hb = __builtin_bit_cast(uint16_t, (f16)hn);
      uint32_t tagged = (want1 << 16) | (uint32_t)hb;
      size_t poff = (size_t)(want1 & 15u) * (BB * DD) + (size_t)batch * DD + e_g;
      *(volatile uint32_t*)(hxF + poff) = tagged;                       // fast: local L2
      __hip_atomic_store(hxS + poff, tagged, __ATOMIC_RELAXED,
                         __HIP_MEMORY_SCOPE_AGENT);                     // slow: fallback
      size_t base = (size_t)t * 16384 + (size_t)batch * DD + e_g;
      float z = hn + xv_c + bgv;
      d_out[base] = hn * z * sigmoid_fast(z);   // out[t]  (overwrites consumed cand_x[t])
      d_out[H0OFF + 16384 + base] = hn;         // h[t+1]  (overwrites consumed delta_raw[t])
      h_own = hn; cx_c = cx_n; dr_c = dr_n; xv_c = xv_n;
    }
  }
}

// ---------------- launch ----------------
extern "C" void kernel_launch(void* const* d_in, const int* in_sizes, int n_in,
                              void* d_out_v, int out_size, void* d_ws, size_t ws_size,
                              hipStream_t stream) {
  const float* x  = (const float*)d_in[0];
  const float* h0 = (const float*)d_in[1];
  const float* Wx = (const float*)d_in[2];
  const float* Wh = (const float*)d_in[3];
  const float* Wd = (const float*)d_in[4];
  const float* b  = (const float*)d_in[5];
  const float* bd = (const float*)d_in[6];
  const float* bg = (const float*)d_in[7];
  float* out = (float*)d_out_v;

  char* ws = (char*)d_ws;
  float* u    = (float*)(ws + 0);
  float* v    = (float*)(ws + 4096);
  float* t0   = (float*)(ws + 8192);
  float* sc   = (float*)(ws + 12288);
  uint32_t* hxF = (uint32_t*)(ws + 65536);       // fast exchange: 16*16*1024*4 = 1 MiB
  uint32_t* hxS = (uint32_t*)(ws + 1114112);     // slow exchange: 1 MiB
  f16* WhH  = (f16*)(ws + 4194304);              // 2 MiB at 4 MiB offset

  // clear both exchange buffers (first-call garbage could alias a valid tag)
  (void)hipMemsetAsync(hxF, 0, (size_t)16 * BB * DD * 4, stream);
  (void)hipMemsetAsync(hxS, 0, (size_t)16 * BB * DD * 4, stream);

  k_u0<<<1, 512, 0, stream>>>(t0, u);
  for (int it = 0; it < 3; ++it) {
    k_mvT<<<4, 256, 0, stream>>>(Wh, u, t0);
    k_norm<<<1, 1024, 0, stream>>>(t0, v, 1e-8f);
    k_mv<<<16, 256, 0, stream>>>(Wh, v, t0);
    k_norm<<<1, 1024, 0, stream>>>(t0, u, 1e-8f);
  }
  k_sigma<<<1, 1024, 0, stream>>>(u, t0, sc);
  k_castWh<<<4096, 256, 0, stream>>>(Wh, sc, WhH);

  dim3 gg(256, 8, 1);
  k_gemm<<<gg, 256, 0, stream>>>(x, Wx, b, out);                   // cand_x -> out region
  k_gemm<<<gg, 256, 0, stream>>>(x, Wd, bd, out + H0OFF + 16384);  // delta_raw -> h region (+1)

  k_rec<<<256, 512, 0, stream>>>(x, h0, bg, WhH, hxF, hxS, out);
}